// Round 9
// baseline (119.128 us; speedup 1.0000x reference)
//
#include <hip/hip_runtime.h>
#include <hip/hip_bf16.h>
#include <cstdint>

#define HDIM 2048
#define INDIM 4096
#define CDIM 4096
#define KDIM 2048   // GEMM K = hidden size

typedef __attribute__((ext_vector_type(4))) int int4v;

__device__ __forceinline__ void gload16(const void* g, void* l) {
  __builtin_amdgcn_global_load_lds(
      (const __attribute__((address_space(1))) void*)g,
      (__attribute__((address_space(3))) void*)l, 16, 0, 0);
}

// Pin: all previously-issued loads must complete here; memory clobber keeps
// the compiler from sinking the loads past this point (burst-issue/burst-wait).
#define LOADPIN() asm volatile("s_waitcnt vmcnt(0)" ::: "memory")

// ---------------- Kernel 1: quant + xa2 GEMV + W_hh gate partials -------------
// blocks [0,1536):     i8 row-quant of c_input/aW_hh (wave-per-row, 6144 rows)
// blocks [1536,2048):  xa2[h] = x @ aW_ih[h] + ab_ih[h] + ab_hh[h]
// blocks [2048,3584):  gate_part[vr] = h0 @ W_hh[grow] + b_ih[grow] + b_hh[grow]
__global__ __launch_bounds__(256) void k_prep(
    const float* __restrict__ c_input, const float* __restrict__ aW_hh,
    int8_t* __restrict__ a8, int8_t* __restrict__ b8,
    float* __restrict__ dAs, float* __restrict__ dBs,
    const float* __restrict__ x, const float* __restrict__ h0,
    const float* __restrict__ aW_ih, const float* __restrict__ ab_ih,
    const float* __restrict__ ab_hh,
    const float* __restrict__ W_hh, const float* __restrict__ b_ih,
    const float* __restrict__ b_hh,
    float* __restrict__ xa2, float* __restrict__ gate_part,
    float* __restrict__ accz) {
  const int t = threadIdx.x;
  const int wid = t >> 6, lane = t & 63;

  if (blockIdx.x < 1536) {
    if (blockIdx.x == 0) {  // zero acc_se/acc_sce (4096 floats) every launch
#pragma unroll
      for (int i = 0; i < 16; ++i) accz[i * 256 + t] = 0.f;
    }
    const int row = blockIdx.x * 4 + wid;
    const float* src; int8_t* dst; float* dsc; int r;
    if (row < CDIM) { src = c_input; dst = a8; dsc = dAs; r = row; }
    else            { src = aW_hh;  dst = b8; dsc = dBs; r = row - CDIM; }
    const float4* s4 = (const float4*)(src + (size_t)r * KDIM);
    float4 v[8];
#pragma unroll
    for (int it = 0; it < 8; ++it) v[it] = s4[it * 64 + lane];
    LOADPIN();
    float am = 0.f;
#pragma unroll
    for (int it = 0; it < 8; ++it)
      am = fmaxf(am, fmaxf(fmaxf(fabsf(v[it].x), fabsf(v[it].y)),
                           fmaxf(fabsf(v[it].z), fabsf(v[it].w))));
#pragma unroll
    for (int off = 32; off > 0; off >>= 1) am = fmaxf(am, __shfl_xor(am, off));
    am = fmaxf(am, 1e-20f);
    const float inv = 127.0f / am;
    uint32_t* qd = (uint32_t*)(dst + (size_t)r * KDIM);
#pragma unroll
    for (int it = 0; it < 8; ++it) {
      uint32_t p = (uint32_t)(__float2int_rn(v[it].x * inv) & 0xFF)
                 | ((uint32_t)(__float2int_rn(v[it].y * inv) & 0xFF) << 8)
                 | ((uint32_t)(__float2int_rn(v[it].z * inv) & 0xFF) << 16)
                 | ((uint32_t)(__float2int_rn(v[it].w * inv) & 0xFF) << 24);
      qd[it * 64 + lane] = p;
    }
    if (lane == 0) dsc[r] = am * (1.0f / 127.0f);
    return;
  }

  if (blockIdx.x < 2048) {
    // ---- xa2 GEMV: one wave per h ----
    const int h = (blockIdx.x - 1536) * 4 + wid;
    const float4* x4 = (const float4*)x;
    const float4* wr4 = (const float4*)(aW_ih + (size_t)h * INDIM);
    float sum = 0.f;
#pragma unroll
    for (int g = 0; g < 2; ++g) {
      float4 w[8];
#pragma unroll
      for (int it = 0; it < 8; ++it) w[it] = wr4[(g * 8 + it) * 64 + lane];
      LOADPIN();
#pragma unroll
      for (int it = 0; it < 8; ++it) {
        float4 xv = x4[(g * 8 + it) * 64 + lane];
        sum += w[it].x * xv.x + w[it].y * xv.y + w[it].z * xv.z + w[it].w * xv.w;
      }
    }
#pragma unroll
    for (int off = 32; off > 0; off >>= 1) sum += __shfl_down(sum, off);
    if (lane == 0) xa2[h] = sum + ab_ih[h] + ab_hh[h];
    return;
  }

  // ---- W_hh gate partials: one wave per virtual row ----
  const int vr = (blockIdx.x - 2048) * 4 + wid;  // [0, 6144)
  const int typ = vr >> 11;                      // 0=i, 1=o, 2=g
  const int h = vr & (HDIM - 1);
  const int grow = (typ == 0) ? h : (typ == 1) ? (2 * HDIM + h) : (3 * HDIM + h);
  const float4* wh4 = (const float4*)(W_hh + (size_t)grow * HDIM);
  const float4* h4 = (const float4*)h0;
  float sum = 0.f;
  {
    float4 w[8];
#pragma unroll
    for (int it = 0; it < 8; ++it) w[it] = wh4[it * 64 + lane];
    LOADPIN();
#pragma unroll
    for (int it = 0; it < 8; ++it) {
      float4 hv = h4[it * 64 + lane];
      sum += w[it].x * hv.x + w[it].y * hv.y + w[it].z * hv.z + w[it].w * hv.w;
    }
  }
#pragma unroll
  for (int off = 32; off > 0; off >>= 1) sum += __shfl_down(sum, off);
  if (lane == 0) gate_part[vr] = sum + b_ih[grow] + b_hh[grow];
}

// ---------------- Kernel 2: fat kernel = i8 GEMM interleaved with gate GEMVs --
// ROLE INTERLEAVE (r8 post-mortem): blocks dispatch to XCD bid%8, then pack
// depth-first within the XCD. Role must therefore alternate in PER-XCD fill
// order (bid>>3), not in raw bid. GEMM iff ((bid>>3)&3)==0: any 4 consecutive
// blocks of one XCD's fill sequence = exactly 1 GEMM + 3 GEMV -> every CU gets
// ~4 GEMM + ~12 GEMV waves regardless of packing policy. This is what makes
// the GEMV streaming actually hide under MFMA (m114) — the bid<512 split gave
// zero co-residency (r5-r8 all ~65-68 us).
// GEMM (512 tiles): 128x128, BK=64 dbuf (32 KB LDS), mfma_i32_16x16x64_i8,
//   fused sigmoid/exp/column-reduce epilogue; epilogue now dequants a8 (i8,
//   L2-warm) instead of re-reading c_input fp32 (-32 MB HBM; +~1e-4 error).
// GEMV (1536 blocks): z = x @ W_ih[grow] + gate_part[vr] (w[16] burst+pin).
// LDS swizzle p(r) = ((r>>1)&3)<<4: 2-way residual = free (r6 fix, verified 0).
__global__ __launch_bounds__(256, 4) void k_gemm_gemv(
    const int8_t* __restrict__ A, const int8_t* __restrict__ B,
    const float* __restrict__ dAs, const float* __restrict__ dBs,
    const float* __restrict__ xa2,
    float* __restrict__ acc_se, float* __restrict__ acc_sce,
    const float* __restrict__ x, const float* __restrict__ W_ih,
    const float* __restrict__ gate_part,
    float* __restrict__ i_sig, float* __restrict__ o_sig,
    float* __restrict__ g_tanh) {
  __shared__ uint8_t As[2][8192];  // 128 rows x 64 k-bytes, double-buffered
  __shared__ uint8_t Bs[2][8192];
  const int t = threadIdx.x;
  const int lane = t & 63, wid = t >> 6;
  const int bid = blockIdx.x;
  const int slot = (bid >> 3) & 3;   // position in per-XCD fill order, mod 4
  const int q = bid >> 5, r8xcd = bid & 7;

  if (slot == 0) {
    // ================= GEMM path: tile t = q*8 + r8xcd ∈ [0,512) ============
    const int wr = wid >> 1, wc = wid & 1;
    const int l15 = lane & 15, l4 = lane >> 4;
    const int bn = r8xcd * 2 + (q & 1);  // XCD-grouped B panels (L2 locality)
    const int bm = q >> 1;
    const int m0 = bm * 128, n0 = bn * 128;

    int4v acc[4][4] = {};

    const int trow = t >> 2;
    const int tcol = (((t & 3) ^ ((trow >> 1) & 3)) * 16);  // pre-swizzled src
    const int8_t* Arow = A + (size_t)(m0 + trow) * KDIM + tcol;
    const int8_t* Brow = B + (size_t)(n0 + trow) * KDIM + tcol;

#define STAGE(buf, k0)                                                          \
    do {                                                                        \
      _Pragma("unroll")                                                         \
      for (int qq = 0; qq < 2; ++qq) {                                          \
        gload16(Arow + (size_t)qq * 64 * KDIM + (k0), As[buf] + qq * 4096 + t * 16); \
        gload16(Brow + (size_t)qq * 64 * KDIM + (k0), Bs[buf] + qq * 4096 + t * 16); \
      }                                                                         \
    } while (0)

    STAGE(0, 0);
    __syncthreads();  // implicit vmcnt(0) drain -> buf0 ready

    int cur = 0;
    for (int ti = 0; ti < KDIM / 64; ++ti) {  // 32 iterations
      if (ti < KDIM / 64 - 1) STAGE(cur ^ 1, (ti + 1) * 64);
      int4v af[4], bfr[4];
#pragma unroll
      for (int m = 0; m < 4; ++m) {
        const int rr = wr * 64 + m * 16 + l15;
        af[m] = *(const int4v*)(As[cur] + rr * 64 + ((l4 ^ ((rr >> 1) & 3)) * 16));
      }
#pragma unroll
      for (int n = 0; n < 4; ++n) {
        const int rr = wc * 64 + n * 16 + l15;
        bfr[n] = *(const int4v*)(Bs[cur] + rr * 64 + ((l4 ^ ((rr >> 1) & 3)) * 16));
      }
#pragma unroll
      for (int m = 0; m < 4; ++m)
#pragma unroll
        for (int n = 0; n < 4; ++n)
          acc[m][n] = __builtin_amdgcn_mfma_i32_16x16x64_i8(af[m], bfr[n], acc[m][n], 0, 0, 0);
      __syncthreads();  // reads of cur done; staging into cur^1 drained
      cur ^= 1;
    }
#undef STAGE

    // epilogue: D layout col = lane&15, row = (lane>>4)*4 + reg [m89-verified]
    // merge term dequants a8 (i8, L2-warm) -> no 32 MB c_input fp32 re-read.
#pragma unroll
    for (int n = 0; n < 4; ++n) {
      const int hcol = n0 + wc * 64 + n * 16 + l15;
      const float xa = xa2[hcol];
      const float db = dBs[hcol];
      float se = 0.f, sce = 0.f;
#pragma unroll
      for (int m = 0; m < 4; ++m) {
        const int jbase = m0 + wr * 64 + m * 16 + l4 * 4;
#pragma unroll
        for (int rr = 0; rr < 4; ++rr) {
          const float da = dAs[jbase + rr];
          float z = (float)acc[m][n][rr] * (da * db) + xa;
          float s = 1.f / (1.f + __expf(-z));
          float e = __expf(s);
          se += e;
          sce += (float)A[(size_t)(jbase + rr) * KDIM + hcol] * (da * e);
        }
      }
      se += __shfl_xor(se, 16); se += __shfl_xor(se, 32);
      sce += __shfl_xor(sce, 16); sce += __shfl_xor(sce, 32);
      if (l4 == 0) {
        atomicAdd(&acc_se[hcol], se);
        atomicAdd(&acc_sce[hcol], sce);
      }
    }
    return;
  }

  // ================= gate GEMV path: z = x @ W_ih[grow] + gate_part ==========
  const int vid = (q * 3 + (slot - 1)) * 8 + r8xcd;  // [0, 1536) bijective
  const int vr = vid * 4 + wid;                      // [0, 6144)
  const int typ = vr >> 11;                          // 0=i, 1=o, 2=g
  const int h = vr & (HDIM - 1);
  const int grow = (typ == 0) ? h : (typ == 1) ? (2 * HDIM + h) : (3 * HDIM + h);
  const float4* x4 = (const float4*)x;
  const float4* wr4 = (const float4*)(W_ih + (size_t)grow * INDIM);
  float sum = 0.f;
  {
    float4 w[16];  // 64 VGPR burst: 16 dwordx4 in flight before the pin
#pragma unroll
    for (int it = 0; it < 16; ++it) w[it] = wr4[it * 64 + lane];
    LOADPIN();
#pragma unroll
    for (int it = 0; it < 16; ++it) {
      float4 xv = x4[it * 64 + lane];
      sum += w[it].x * xv.x + w[it].y * xv.y + w[it].z * xv.z + w[it].w * xv.w;
    }
  }
#pragma unroll
  for (int off = 32; off > 0; off >>= 1) sum += __shfl_down(sum, off);
  if (lane == 0) {
    float z = sum + gate_part[vr];
    if (typ == 0)      i_sig[h] = 1.f / (1.f + expf(-z));
    else if (typ == 1) o_sig[h] = 1.f / (1.f + expf(-z));
    else               g_tanh[h] = tanhf(z);
  }
}

// ---------------- Kernel 3: finalize ------------------------------------------
__global__ __launch_bounds__(256) void k_final(
    const float* __restrict__ i_sig, const float* __restrict__ o_sig,
    const float* __restrict__ g_tanh, const float* __restrict__ acc_se,
    const float* __restrict__ acc_sce, float* __restrict__ out) {
  int h = blockIdx.x * 256 + threadIdx.x;
  if (h >= HDIM) return;
  float wi = expf(i_sig[h]);
  float tot = acc_se[h] + wi;
  float c1 = (acc_sce[h] + g_tanh[h] * wi) / tot;
  float h1 = o_sig[h] * tanhf(c1);
  out[h] = h1;
  out[HDIM + h] = c1;
}

extern "C" void kernel_launch(void* const* d_in, const int* in_sizes, int n_in,
                              void* d_out, int out_size, void* d_ws, size_t ws_size,
                              hipStream_t stream) {
  const float* x     = (const float*)d_in[0];
  const float* c_inp = (const float*)d_in[1];
  const float* h0    = (const float*)d_in[2];
  // d_in[3] = c0: unused by the reference output
  const float* W_ih  = (const float*)d_in[4];
  const float* b_ih  = (const float*)d_in[5];
  const float* W_hh  = (const float*)d_in[6];
  const float* b_hh  = (const float*)d_in[7];
  const float* aW_ih = (const float*)d_in[8];
  const float* ab_ih = (const float*)d_in[9];
  const float* aW_hh = (const float*)d_in[10];
  const float* ab_hh = (const float*)d_in[11];
  float* out = (float*)d_out;

  char* ws = (char*)d_ws;
  int8_t* a8 = (int8_t*)ws;                          // 8 MB i8 c_input
  int8_t* b8 = a8 + (size_t)CDIM * KDIM;             // 4 MB i8 aW_hh
  float* dAs = (float*)(b8 + (size_t)HDIM * KDIM);   // 16 KB row scales A
  float* dBs = dAs + CDIM;                           // 8 KB row scales B
  float* fb  = dBs + HDIM;
  float* i_sig    = fb;
  float* o_sig    = fb + HDIM;
  float* g_tanh   = fb + 2 * HDIM;
  float* xa2      = fb + 3 * HDIM;
  float* acc_se   = fb + 4 * HDIM;  // acc_se/acc_sce contiguous: zeroed together
  float* acc_sce  = fb + 5 * HDIM;
  float* gate_part = fb + 6 * HDIM;  // 3*HDIM floats (i,o,g partials)

  // k1: 1536 quant + 512 xa2 + 1536 W_hh-partial blocks
  k_prep<<<3584, 256, 0, stream>>>(
      c_inp, aW_hh, a8, b8, dAs, dBs, x, h0, aW_ih, ab_ih, ab_hh,
      W_hh, b_ih, b_hh, xa2, gate_part, acc_se);
  // k2: 2048 blocks; role interleaved in per-XCD fill order (1 GEMM : 3 GEMV)
  k_gemm_gemv<<<2048, 256, 0, stream>>>(
      a8, b8, dAs, dBs, xa2, acc_se, acc_sce,
      x, W_ih, gate_part, i_sig, o_sig, g_tanh);
  k_final<<<(HDIM + 255) / 256, 256, 0, stream>>>(i_sig, o_sig, g_tanh,
                                                  acc_se, acc_sce, out);
}

// Round 11
// 65.835 us; speedup vs baseline: 1.8095x; 1.8095x over previous
//
#include <hip/hip_runtime.h>
#include <hip/hip_bf16.h>
#include <cstdint>

#define HDIM 2048
#define INDIM 4096
#define CDIM 4096
#define KDIM 2048   // GEMM K = hidden size

typedef __attribute__((ext_vector_type(4))) int int4v;

__device__ __forceinline__ void gload16(const void* g, void* l) {
  __builtin_amdgcn_global_load_lds(
      (const __attribute__((address_space(1))) void*)g,
      (__attribute__((address_space(3))) void*)l, 16, 0, 0);
}

#define LOADPIN() asm volatile("s_waitcnt vmcnt(0)" ::: "memory")
// raw workgroup barrier, order-pinned both directions (rule #18: sched_barrier
// stops hipcc moving LDS reads / MFMA across the inline barrier)
#define WGBAR()                                   \
  do {                                            \
    __builtin_amdgcn_sched_barrier(0);            \
    __builtin_amdgcn_s_barrier();                 \
    __builtin_amdgcn_sched_barrier(0);            \
  } while (0)

__device__ __forceinline__ float dot4(float4 a, float4 b) {
  return a.x * b.x + a.y * b.y + a.z * b.z + a.w * b.w;
}

// ---------------- Kernel 1: quant + xa2 GEMV + W_hh gate partials -------------
// blocks [0,1536):     i8 row-quant of c_input/aW_hh (wave-per-row, 6144 rows)
// blocks [1536,2048):  xa2[h] = x @ aW_ih[h] + ab_ih[h] + ab_hh[h]
// blocks [2048,3584):  gate_part[vr] = h0 @ W_hh[grow] + b_ih[grow] + b_hh[grow]
//                      layout: vr = typ*HDIM + h, typ in {0:i, 1:o, 2:g}
__global__ __launch_bounds__(256) void k_prep(
    const float* __restrict__ c_input, const float* __restrict__ aW_hh,
    int8_t* __restrict__ a8, int8_t* __restrict__ b8,
    float* __restrict__ dAs, float* __restrict__ dBs,
    const float* __restrict__ x, const float* __restrict__ h0,
    const float* __restrict__ aW_ih, const float* __restrict__ ab_ih,
    const float* __restrict__ ab_hh,
    const float* __restrict__ W_hh, const float* __restrict__ b_ih,
    const float* __restrict__ b_hh,
    float* __restrict__ xa2, float* __restrict__ gate_part,
    float* __restrict__ accz) {
  const int t = threadIdx.x;
  const int wid = t >> 6, lane = t & 63;

  if (blockIdx.x < 1536) {
    if (blockIdx.x == 0) {  // zero acc_se/acc_sce (4096 floats) every launch
#pragma unroll
      for (int i = 0; i < 16; ++i) accz[i * 256 + t] = 0.f;
    }
    const int row = blockIdx.x * 4 + wid;
    const float* src; int8_t* dst; float* dsc; int r;
    if (row < CDIM) { src = c_input; dst = a8; dsc = dAs; r = row; }
    else            { src = aW_hh;  dst = b8; dsc = dBs; r = row - CDIM; }
    const float4* s4 = (const float4*)(src + (size_t)r * KDIM);
    float4 v[8];
#pragma unroll
    for (int it = 0; it < 8; ++it) v[it] = s4[it * 64 + lane];
    LOADPIN();
    float am = 0.f;
#pragma unroll
    for (int it = 0; it < 8; ++it)
      am = fmaxf(am, fmaxf(fmaxf(fabsf(v[it].x), fabsf(v[it].y)),
                           fmaxf(fabsf(v[it].z), fabsf(v[it].w))));
#pragma unroll
    for (int off = 32; off > 0; off >>= 1) am = fmaxf(am, __shfl_xor(am, off));
    am = fmaxf(am, 1e-20f);
    const float inv = 127.0f / am;
    uint32_t* qd = (uint32_t*)(dst + (size_t)r * KDIM);
#pragma unroll
    for (int it = 0; it < 8; ++it) {
      uint32_t p = (uint32_t)(__float2int_rn(v[it].x * inv) & 0xFF)
                 | ((uint32_t)(__float2int_rn(v[it].y * inv) & 0xFF) << 8)
                 | ((uint32_t)(__float2int_rn(v[it].z * inv) & 0xFF) << 16)
                 | ((uint32_t)(__float2int_rn(v[it].w * inv) & 0xFF) << 24);
      qd[it * 64 + lane] = p;
    }
    if (lane == 0) dsc[r] = am * (1.0f / 127.0f);
    return;
  }

  if (blockIdx.x < 2048) {
    // ---- xa2 GEMV: one wave per h ----
    const int h = (blockIdx.x - 1536) * 4 + wid;
    const float4* x4 = (const float4*)x;
    const float4* wr4 = (const float4*)(aW_ih + (size_t)h * INDIM);
    float sum = 0.f;
#pragma unroll
    for (int g = 0; g < 2; ++g) {
      float4 w[8];
#pragma unroll
      for (int it = 0; it < 8; ++it) w[it] = wr4[(g * 8 + it) * 64 + lane];
      LOADPIN();
#pragma unroll
      for (int it = 0; it < 8; ++it) {
        float4 xv = x4[(g * 8 + it) * 64 + lane];
        sum += dot4(w[it], xv);
      }
    }
#pragma unroll
    for (int off = 32; off > 0; off >>= 1) sum += __shfl_down(sum, off);
    if (lane == 0) xa2[h] = sum + ab_ih[h] + ab_hh[h];
    return;
  }

  // ---- W_hh gate partials: one wave per virtual row ----
  const int vr = (blockIdx.x - 2048) * 4 + wid;  // [0, 6144)
  const int typ = vr >> 11;                      // 0=i, 1=o, 2=g
  const int h = vr & (HDIM - 1);
  const int grow = (typ == 0) ? h : (typ == 1) ? (2 * HDIM + h) : (3 * HDIM + h);
  const float4* wh4 = (const float4*)(W_hh + (size_t)grow * HDIM);
  const float4* h4 = (const float4*)h0;
  float sum = 0.f;
  {
    float4 w[8];
#pragma unroll
    for (int it = 0; it < 8; ++it) w[it] = wh4[it * 64 + lane];
    LOADPIN();
#pragma unroll
    for (int it = 0; it < 8; ++it) sum += dot4(w[it], h4[it * 64 + lane]);
  }
#pragma unroll
  for (int off = 32; off > 0; off >>= 1) sum += __shfl_down(sum, off);
  if (lane == 0) gate_part[vr] = sum + b_ih[grow] + b_hh[grow];
}

// ---------------- Kernel 2: wave-specialized lockstep fused kernel ------------
// 512 blocks x 512 threads (= 2 blocks/CU, 8 GEMM + 8 GEMV waves per CU).
// Waves 0-3: i8 GEMM, 128x128 tile, BK=64, double-buffered LDS with RAW
//   s_barrier (no __syncthreads vmcnt(0)-drain coupling; each GEMM wave drains
//   only ITS OWN 4 staging loads, which are L3-fast — a8/b8 = 12 MB resident).
// Waves 4-7: W_ih gate streaming (rows i/o/g of one h per wave), issue 2
//   dwordx4 per segment, consume 2 barriers later (counted vmcnt by compiler)
//   — HBM latency hides inside the barrier wait.
// BOTH paths execute exactly 33 s_barriers (1 prologue + 32 loop).
// r10 bug fixed: gate_part is indexed [typ*HDIM + h] (o at HDIM+h, g at
// 2*HDIM+h) — NOT the W_ih row offsets 2/3*HDIM (r10 read garbage for g).
// LDS swizzle p(r)=((r>>1)&3): 2-way residual = free (r6 fix, verified 0).
__global__ __launch_bounds__(512, 4) void k_fused(
    const int8_t* __restrict__ A, const int8_t* __restrict__ B,
    const float* __restrict__ dAs, const float* __restrict__ dBs,
    const float* __restrict__ c_in, const float* __restrict__ xa2,
    float* __restrict__ acc_se, float* __restrict__ acc_sce,
    const float* __restrict__ x, const float* __restrict__ W_ih,
    const float* __restrict__ gate_part,
    float* __restrict__ i_sig, float* __restrict__ o_sig,
    float* __restrict__ g_tanh) {
  __shared__ uint8_t As[2][8192];  // 128 rows x 64 k-bytes
  __shared__ uint8_t Bs[2][8192];
  const int t = threadIdx.x;
  const int lane = t & 63, wid = t >> 6;
  const int bid = blockIdx.x;

  if (wid < 4) {
    // ================= GEMM waves (threads 0..255) =================
    const int wr = wid >> 1, wc = wid & 1;
    const int l15 = lane & 15, l4 = lane >> 4;
    const int bn = (bid & 7) * 2 + ((bid >> 3) & 1);  // XCD-grouped B panels
    const int bm = bid >> 4;
    const int m0 = bm * 128, n0 = bn * 128;

    int4v acc[4][4] = {};

    const int trow = t >> 2;
    const int tcol = (((t & 3) ^ ((trow >> 1) & 3)) * 16);  // pre-swizzled src
    const int8_t* Arow = A + (size_t)(m0 + trow) * KDIM + tcol;
    const int8_t* Brow = B + (size_t)(n0 + trow) * KDIM + tcol;

#define STAGE(buf, k0)                                                          \
    do {                                                                        \
      _Pragma("unroll")                                                         \
      for (int qq = 0; qq < 2; ++qq) {                                          \
        gload16(Arow + (size_t)qq * 64 * KDIM + (k0), As[buf] + qq * 4096 + t * 16); \
        gload16(Brow + (size_t)qq * 64 * KDIM + (k0), Bs[buf] + qq * 4096 + t * 16); \
      }                                                                         \
    } while (0)

    STAGE(0, 0);
    LOADPIN();      // my 4 staging loads landed (i8 data: L3-resident, fast)
    WGBAR();        // barrier #0: buf0 complete for all

    int cur = 0;
    for (int ti = 0; ti < 32; ++ti) {
      // ds_read current tile fragments (compiler emits counted lgkmcnt
      // before the MFMAs that consume them -> reads complete before barrier)
      int4v af[4], bfr[4];
#pragma unroll
      for (int m = 0; m < 4; ++m) {
        const int r = wr * 64 + m * 16 + l15;
        af[m] = *(const int4v*)(As[cur] + r * 64 + ((l4 ^ ((r >> 1) & 3)) * 16));
      }
#pragma unroll
      for (int n = 0; n < 4; ++n) {
        const int r = wc * 64 + n * 16 + l15;
        bfr[n] = *(const int4v*)(Bs[cur] + r * 64 + ((l4 ^ ((r >> 1) & 3)) * 16));
      }
      if (ti < 31) STAGE(cur ^ 1, (ti + 1) * 64);  // prefetch next tile
#pragma unroll
      for (int m = 0; m < 4; ++m)
#pragma unroll
        for (int n = 0; n < 4; ++n)
          acc[m][n] = __builtin_amdgcn_mfma_i32_16x16x64_i8(af[m], bfr[n], acc[m][n], 0, 0, 0);
      LOADPIN();    // my staging for buf[cur^1] landed (own loads only)
      WGBAR();      // barriers #1..#32: everyone's staging landed,
                    // everyone done reading buf[cur]
      cur ^= 1;
    }
#undef STAGE

    // epilogue: D layout col = lane&15, row = (lane>>4)*4 + reg [m89-verified]
#pragma unroll
    for (int n = 0; n < 4; ++n) {
      const int hcol = n0 + wc * 64 + n * 16 + l15;
      const float xa = xa2[hcol];
      const float db = dBs[hcol];
      float se = 0.f, sce = 0.f;
#pragma unroll
      for (int m = 0; m < 4; ++m) {
        const int jbase = m0 + wr * 64 + m * 16 + l4 * 4;
#pragma unroll
        for (int rr = 0; rr < 4; ++rr) {
          const float sc = dAs[jbase + rr] * db;
          float z = (float)acc[m][n][rr] * sc + xa;
          float s = 1.f / (1.f + __expf(-z));
          float e = __expf(s);
          se += e;
          sce += c_in[(size_t)(jbase + rr) * HDIM + hcol] * e;  // L3-hot fp32
        }
      }
      se += __shfl_xor(se, 16); se += __shfl_xor(se, 32);
      sce += __shfl_xor(sce, 16); sce += __shfl_xor(sce, 32);
      if (l4 == 0) {
        atomicAdd(&acc_se[hcol], se);
        atomicAdd(&acc_sce[hcol], sce);
      }
    }
    return;
  }

  // ================= GEMV waves (threads 256..511) =================
  // wave handles h = bid*4 + (wid-4); rows i/o/g share the same h.
  // 16 chunks/row; batches A(c)={wI(c),x(c)}, B(c)={wO(c),wG(c)} issued one
  // per segment, consumed 2 segments later. 33 barriers total (lockstep).
  const int h = bid * 4 + (wid - 4);  // [0, 2048)
  const float4* WI = (const float4*)(W_ih + (size_t)h * INDIM);
  const float4* WO = (const float4*)(W_ih + (size_t)(2 * HDIM + h) * INDIM);
  const float4* WG = (const float4*)(W_ih + (size_t)(3 * HDIM + h) * INDIM);
  const float4* x4 = (const float4*)x;
  float sI = 0.f, sO = 0.f, sG = 0.f;
  float4 wI0, wI1, xv0, xv1, wO0, wO1, wG0, wG1;

  wI0 = WI[lane]; xv0 = x4[lane];            // issue A(0)
  WGBAR();                                   // barrier #0
  wO0 = WO[lane]; wG0 = WG[lane];            // seg 0: issue B(0)
  WGBAR();                                   // barrier #1
#pragma unroll
  for (int c = 0; c < 15; ++c) {
    // seg 2c+1: issue A(c+1), consume A(c)
    if ((c & 1) == 0) {
      wI1 = WI[(c + 1) * 64 + lane]; xv1 = x4[(c + 1) * 64 + lane];
      sI += dot4(wI0, xv0);
    } else {
      wI0 = WI[(c + 1) * 64 + lane]; xv0 = x4[(c + 1) * 64 + lane];
      sI += dot4(wI1, xv1);
    }
    WGBAR();
    // seg 2c+2: issue B(c+1), consume B(c)
    if ((c & 1) == 0) {
      wO1 = WO[(c + 1) * 64 + lane]; wG1 = WG[(c + 1) * 64 + lane];
      sO += dot4(wO0, xv0); sG += dot4(wG0, xv0);
    } else {
      wO0 = WO[(c + 1) * 64 + lane]; wG0 = WG[(c + 1) * 64 + lane];
      sO += dot4(wO1, xv1); sG += dot4(wG1, xv1);
    }
    WGBAR();
  }
  // last iteration was c=14 (even) -> chunk 15 lives in the *1 registers
  sI += dot4(wI1, xv1);
  WGBAR();                                   // barrier #32 (the 33rd)
  sO += dot4(wO1, xv1); sG += dot4(wG1, xv1);

#pragma unroll
  for (int off = 32; off > 0; off >>= 1) {
    sI += __shfl_down(sI, off);
    sO += __shfl_down(sO, off);
    sG += __shfl_down(sG, off);
  }
  if (lane == 0) {
    // gate_part layout is [typ*HDIM + h] (r10 bug: used W_ih row offsets)
    float zI = sI + gate_part[h];
    float zO = sO + gate_part[HDIM + h];
    float zG = sG + gate_part[2 * HDIM + h];
    i_sig[h] = 1.f / (1.f + expf(-zI));
    o_sig[h] = 1.f / (1.f + expf(-zO));
    g_tanh[h] = tanhf(zG);
  }
}

// ---------------- Kernel 3: finalize ------------------------------------------
__global__ __launch_bounds__(256) void k_final(
    const float* __restrict__ i_sig, const float* __restrict__ o_sig,
    const float* __restrict__ g_tanh, const float* __restrict__ acc_se,
    const float* __restrict__ acc_sce, float* __restrict__ out) {
  int h = blockIdx.x * 256 + threadIdx.x;
  if (h >= HDIM) return;
  float wi = expf(i_sig[h]);
  float tot = acc_se[h] + wi;
  float c1 = (acc_sce[h] + g_tanh[h] * wi) / tot;
  float h1 = o_sig[h] * tanhf(c1);
  out[h] = h1;
  out[HDIM + h] = c1;
}

extern "C" void kernel_launch(void* const* d_in, const int* in_sizes, int n_in,
                              void* d_out, int out_size, void* d_ws, size_t ws_size,
                              hipStream_t stream) {
  const float* x     = (const float*)d_in[0];
  const float* c_inp = (const float*)d_in[1];
  const float* h0    = (const float*)d_in[2];
  // d_in[3] = c0: unused by the reference output
  const float* W_ih  = (const float*)d_in[4];
  const float* b_ih  = (const float*)d_in[5];
  const float* W_hh  = (const float*)d_in[6];
  const float* b_hh  = (const float*)d_in[7];
  const float* aW_ih = (const float*)d_in[8];
  const float* ab_ih = (const float*)d_in[9];
  const float* aW_hh = (const float*)d_in[10];
  const float* ab_hh = (const float*)d_in[11];
  float* out = (float*)d_out;

  char* ws = (char*)d_ws;
  int8_t* a8 = (int8_t*)ws;                          // 8 MB i8 c_input
  int8_t* b8 = a8 + (size_t)CDIM * KDIM;             // 4 MB i8 aW_hh
  float* dAs = (float*)(b8 + (size_t)HDIM * KDIM);   // 16 KB row scales A
  float* dBs = dAs + CDIM;                           // 8 KB row scales B
  float* fb  = dBs + HDIM;
  float* i_sig    = fb;
  float* o_sig    = fb + HDIM;
  float* g_tanh   = fb + 2 * HDIM;
  float* xa2      = fb + 3 * HDIM;
  float* acc_se   = fb + 4 * HDIM;  // acc_se/acc_sce contiguous: zeroed together
  float* acc_sce  = fb + 5 * HDIM;
  float* gate_part = fb + 6 * HDIM;  // 3*HDIM floats, [typ*HDIM + h]

  // k1: 1536 quant + 512 xa2 + 1536 W_hh-partial blocks
  k_prep<<<3584, 256, 0, stream>>>(
      c_inp, aW_hh, a8, b8, dAs, dBs, x, h0, aW_ih, ab_ih, ab_hh,
      W_hh, b_ih, b_hh, xa2, gate_part, acc_se);
  // k2: 512 blocks x 512 threads, wave-specialized GEMM||GEMV lockstep
  k_fused<<<512, 512, 0, stream>>>(
      a8, b8, dAs, dBs, c_inp, xa2, acc_se, acc_sce,
      x, W_ih, gate_part, i_sig, o_sig, g_tanh);
  k_final<<<(HDIM + 255) / 256, 256, 0, stream>>>(i_sig, o_sig, g_tanh,
                                                  acc_se, acc_sce, out);
}